// Round 16
// baseline (107.591 us; speedup 1.0000x reference)
//
#include <hip/hip_runtime.h>

#define N_NODES 100000
#define DIM 8
#define NB 128                 // nodes per bucket
#define BSHIFT 7               // log2(NB)
#define NBUCKETS ((N_NODES + NB - 1) / NB)   // 782
#define LSROW (NBUCKETS + 1)   // 783 (local-scan row incl. sentinel)
#define G1 2048                // partition blocks
#define ESPAN_MAX 3328         // LDS stage cap for scatter
#define CAP 9728               // max edges per bucket (mean 8184, ~17 sigma)
#define NPER 10                // ceil(CAP / 1024) register-staged edges per thread

// ---------------- fallback (atomic path) ----------------
__global__ void init_neg_kernel(const float* __restrict__ x,
                                float* __restrict__ out, int n4) {
    int i = blockIdx.x * blockDim.x + threadIdx.x;
    if (i < n4) {
        float4 v = reinterpret_cast<const float4*>(x)[i];
        float4 o; o.x = -v.x; o.y = -v.y; o.z = -v.z; o.w = -v.w;
        reinterpret_cast<float4*>(out)[i] = o;
    }
}

__global__ void edge_scatter_atomic(const float* __restrict__ x,
                                    const int* __restrict__ row,
                                    const int* __restrict__ col,
                                    const float* __restrict__ w,
                                    float* __restrict__ out, int nE) {
    int e = blockIdx.x * blockDim.x + threadIdx.x;
    if (e >= nE) return;
    int r = row[e], c = col[e];
    float we = w[e];
    const float4* xr = reinterpret_cast<const float4*>(x + (size_t)r * DIM);
    const float4* xc = reinterpret_cast<const float4*>(x + (size_t)c * DIM);
    float4 a0 = xr[0], a1 = xr[1], b0 = xc[0], b1 = xc[1];
    float* o = out + (size_t)c * DIM;
    atomicAdd(o + 0, (a0.x - b0.x) * we); atomicAdd(o + 1, (a0.y - b0.y) * we);
    atomicAdd(o + 2, (a0.z - b0.z) * we); atomicAdd(o + 3, (a0.w - b0.w) * we);
    atomicAdd(o + 4, (a1.x - b1.x) * we); atomicAdd(o + 5, (a1.y - b1.y) * we);
    atomicAdd(o + 6, (a1.z - b1.z) * we); atomicAdd(o + 7, (a1.w - b1.w) * we);
}

// ---------------- R16 pipeline ----------------
// espan is padded to a multiple of 4 so every block's e0 is 16B-aligned.
// Both hist_scan and scatter2 use the same XCD-chunked vblk swizzle so the
// scatter's col/row/w re-reads hit the L2 warmed by the same XCD's hist pass.

// K1: per-block histogram (int4-vectorized col reads) + LOCAL exclusive scan
__global__ __launch_bounds__(256) void hist_scan_kernel(const int* __restrict__ col,
                                                        int nE, int espan,
                                                        unsigned* __restrict__ L) {
    __shared__ unsigned cnt[NBUCKETS];
    __shared__ unsigned part[256];
    int t = threadIdx.x;
    int p = blockIdx.x;
    int blk = (p & 7) * (G1 / 8) + (p >> 3);   // XCD-chunked swizzle (bijective)
    long e0 = (long)blk * espan;
    long rem = (long)nE - e0;
    int n = (int)(rem > (long)espan ? espan : (rem < 0 ? 0 : rem));

    for (int i = t; i < NBUCKETS; i += 256) cnt[i] = 0;
    __syncthreads();

    const int4* col4 = reinterpret_cast<const int4*>(col + e0);  // e0 16B-aligned
    int nv = n >> 2;
    for (int k = t; k < nv; k += 256) {
        int4 c4 = col4[k];
        atomicAdd(&cnt[((unsigned)c4.x) >> BSHIFT], 1u);
        atomicAdd(&cnt[((unsigned)c4.y) >> BSHIFT], 1u);
        atomicAdd(&cnt[((unsigned)c4.z) >> BSHIFT], 1u);
        atomicAdd(&cnt[((unsigned)c4.w) >> BSHIFT], 1u);
    }
    for (int k = (nv << 2) + t; k < n; k += 256)   // tail (<4)
        atomicAdd(&cnt[((unsigned)col[e0 + k]) >> BSHIFT], 1u);
    __syncthreads();

    unsigned v[4], s = 0;
    #pragma unroll
    for (int j = 0; j < 4; ++j) {
        int b = 4 * t + j;
        v[j] = (b < NBUCKETS) ? cnt[b] : 0u;
        s += v[j];
    }
    part[t] = s; __syncthreads();
    for (int off = 1; off < 256; off <<= 1) {
        unsigned u = (t >= off) ? part[t - off] : 0u;
        __syncthreads();
        part[t] += u; __syncthreads();
    }
    unsigned base = part[t] - s;
    size_t lrow = (size_t)blk * LSROW;
    #pragma unroll
    for (int j = 0; j < 4; ++j) {
        int b = 4 * t + j;
        if (b < NBUCKETS) { L[lrow + b] = base; base += v[j]; }
    }
    if (t == 255) L[lrow + NBUCKETS] = part[255];   // == n
}

// K2: tile transpose  in[R][C] -> out[C][R]
__global__ void transpose_kernel(const unsigned* __restrict__ in,
                                 unsigned* __restrict__ outp, int R, int C) {
    __shared__ unsigned tile[32][33];
    int tx = threadIdx.x, ty = threadIdx.y;
    int c0 = blockIdx.x * 32, r0 = blockIdx.y * 32;
    #pragma unroll
    for (int j = 0; j < 32; j += 8) {
        int r = r0 + ty + j, c = c0 + tx;
        if (r < R && c < C) tile[ty + j][tx] = in[(size_t)r * C + c];
    }
    __syncthreads();
    #pragma unroll
    for (int j = 0; j < 32; j += 8) {
        int c = c0 + ty + j, r = r0 + tx;
        if (r < R && c < C) outp[(size_t)c * R + r] = tile[tx][ty + j];
    }
}

// K3: per-bucket cross-block scan (coalesced rows of LT) -> OT, bucketTotal
__global__ __launch_bounds__(1024) void col_scan_kernel(const unsigned* __restrict__ LT,
                                                        unsigned* __restrict__ OT,
                                                        unsigned* __restrict__ bucketTotal) {
    __shared__ unsigned part[1024];
    int b = blockIdx.x, t = threadIdx.x;
    const unsigned* r0 = LT + (size_t)b * G1;
    const unsigned* r1 = LT + (size_t)(b + 1) * G1;
    unsigned c0 = r1[2 * t] - r0[2 * t];
    unsigned c1 = r1[2 * t + 1] - r0[2 * t + 1];
    part[t] = c0 + c1; __syncthreads();
    for (int off = 1; off < 1024; off <<= 1) {
        unsigned u = (t >= off) ? part[t - off] : 0u;
        __syncthreads();
        part[t] += u; __syncthreads();
    }
    unsigned ex = part[t] - (c0 + c1);
    OT[(size_t)b * G1 + 2 * t]     = ex;
    OT[(size_t)b * G1 + 2 * t + 1] = ex + c0;
    if (t == 1023) bucketTotal[b] = part[1023];
}

// K4: exclusive scan over bucket totals
__global__ __launch_bounds__(1024) void bucket_scan_kernel(const unsigned* __restrict__ bucketTotal,
                                                           unsigned* __restrict__ bucketStart) {
    __shared__ unsigned sc[1024];
    int t = threadIdx.x;
    unsigned v = (t < NBUCKETS) ? bucketTotal[t] : 0u;
    sc[t] = v; __syncthreads();
    for (int off = 1; off < 1024; off <<= 1) {
        unsigned u = (t >= off) ? sc[t - off] : 0u;
        __syncthreads();
        sc[t] += u; __syncthreads();
    }
    if (t < NBUCKETS) bucketStart[t] = sc[t] - v;
    if (t == NBUCKETS - 1) bucketStart[NBUCKETS] = sc[t];
}

// K5: blockOffs[blk][b] = OT[b][blk] + bucketStart[b]  (tile transpose)
__global__ void add_transpose_kernel(const unsigned* __restrict__ OT,
                                     const unsigned* __restrict__ bucketStart,
                                     unsigned* __restrict__ blockOffs) {
    __shared__ unsigned tile[32][33];
    int tx = threadIdx.x, ty = threadIdx.y;
    int blk0 = blockIdx.x * 32, b0 = blockIdx.y * 32;
    #pragma unroll
    for (int j = 0; j < 32; j += 8) {
        int b = b0 + ty + j, blk = blk0 + tx;
        if (b < NBUCKETS && blk < G1)
            tile[ty + j][tx] = OT[(size_t)b * G1 + blk] + bucketStart[b];
    }
    __syncthreads();
    #pragma unroll
    for (int j = 0; j < 32; j += 8) {
        int blk = blk0 + ty + j, b = b0 + tx;
        if (b < NBUCKETS && blk < G1)
            blockOffs[(size_t)blk * NBUCKETS + b] = tile[tx][ty + j];
    }
}

// K6: single-pass local sort (2-edge vectorized) + coalesced run-flush.
__global__ __launch_bounds__(512) void scatter2_kernel(
        const int* __restrict__ row,
        const int* __restrict__ col,
        const float* __restrict__ w,
        int nE, int espan,
        const unsigned* __restrict__ L,
        const unsigned* __restrict__ blockOffs,
        uint2* __restrict__ payloadA) {
    __shared__ uint2 stage[ESPAN_MAX];           // 26.6 KB
    __shared__ unsigned short sbkt[ESPAN_MAX];   // 6.7 KB
    __shared__ unsigned cur[NBUCKETS];           // 3.1 KB
    __shared__ unsigned diff[NBUCKETS];          // 3.1 KB
    int t = threadIdx.x;
    int p = blockIdx.x;
    int v = (p & 7) * (G1 / 8) + (p >> 3);       // chunked XCD swizzle (bijective)
    long e0 = (long)v * espan;
    long rem = (long)nE - e0;
    int n = (int)(rem > (long)espan ? espan : (rem < 0 ? 0 : rem));
    size_t lrow = (size_t)v * LSROW;

    for (int i = t; i < NBUCKETS; i += 512) {
        unsigned lv = L[lrow + i];
        cur[i]  = lv;
        diff[i] = blockOffs[(size_t)v * NBUCKETS + i] - lv;
    }
    __syncthreads();

    // sort pass: 2 edges per thread-round (8B-aligned vector loads)
    const int2*   col2 = reinterpret_cast<const int2*>(col + e0);
    const int2*   row2 = reinterpret_cast<const int2*>(row + e0);
    const float2* w2   = reinterpret_cast<const float2*>(w + e0);
    int nv = n >> 1;
    for (int k = t; k < nv; k += 512) {
        int2 c2 = col2[k];
        int2 r2 = row2[k];
        float2 wv = w2[k];
        unsigned b0 = ((unsigned)c2.x) >> BSHIFT;
        unsigned pos0 = atomicAdd(&cur[b0], 1u);
        stage[pos0] = make_uint2(((unsigned)r2.x << BSHIFT) | ((unsigned)c2.x & (NB - 1)),
                                 __float_as_uint(wv.x));
        sbkt[pos0] = (unsigned short)b0;
        unsigned b1 = ((unsigned)c2.y) >> BSHIFT;
        unsigned pos1 = atomicAdd(&cur[b1], 1u);
        stage[pos1] = make_uint2(((unsigned)r2.y << BSHIFT) | ((unsigned)c2.y & (NB - 1)),
                                 __float_as_uint(wv.y));
        sbkt[pos1] = (unsigned short)b1;
    }
    for (int k = (nv << 1) + t; k < n; k += 512) {   // odd tail
        unsigned c = (unsigned)col[e0 + k];
        unsigned b = c >> BSHIFT;
        unsigned pos = atomicAdd(&cur[b], 1u);
        stage[pos] = make_uint2(((unsigned)row[e0 + k] << BSHIFT) | (c & (NB - 1)),
                                __float_as_uint(w[e0 + k]));
        sbkt[pos] = (unsigned short)b;
    }
    __syncthreads();

    for (int k = t; k < n; k += 512) {
        unsigned b = sbkt[k];
        payloadA[diff[b] + (unsigned)k] = stage[k];
    }
}

// K7 (fused, 1024 threads, register-staged, unroll-8 gather)
__global__ __launch_bounds__(1024) void bucket_sort_gather_kernel(
        const float* __restrict__ x,
        const uint2* __restrict__ payloadA,
        const unsigned* __restrict__ bucketStart,
        float* __restrict__ out) {
    __shared__ uint2 stage[CAP];          // 76 KB
    __shared__ unsigned cnt[NB];
    __shared__ unsigned scanb[NB];
    __shared__ unsigned exs[NB + 1];
    int b = blockIdx.x, t = threadIdx.x;
    int e0 = (int)bucketStart[b], e1 = (int)bucketStart[b + 1];
    int n = e1 - e0;

    if (t < NB) cnt[t] = 0;
    __syncthreads();

    if (n <= CAP) {
        // pass 1: coalesced load into registers + count
        uint2 regs[NPER];
        #pragma unroll
        for (int j = 0; j < NPER; ++j) {
            int k = (j << 10) + t;
            if (k < n) {
                uint2 p = payloadA[e0 + k];
                regs[j] = p;
                atomicAdd(&cnt[p.x & (NB - 1)], 1u);
            }
        }
        __syncthreads();
        if (t < NB) scanb[t] = cnt[t];
        __syncthreads();
        for (int off = 1; off < NB; off <<= 1) {
            unsigned v = 0;
            if (t < NB && t >= off) v = scanb[t - off];
            __syncthreads();
            if (t < NB) scanb[t] += v;
            __syncthreads();
        }
        if (t < NB) {
            unsigned ex = scanb[t] - cnt[t];
            exs[t] = ex;
            cnt[t] = ex;                  // cursor
        }
        if (t == 0) exs[NB] = (unsigned)n;
        __syncthreads();

        // pass 2: place from registers (no global re-read)
        #pragma unroll
        for (int j = 0; j < NPER; ++j) {
            int k = (j << 10) + t;
            if (k < n) {
                uint2 p = regs[j];
                unsigned node = p.x & (NB - 1);
                unsigned pos = atomicAdd(&cnt[node], 1u);
                stage[pos] = make_uint2(p.x >> BSHIFT, p.y);
            }
        }
        __syncthreads();

        // gather: one (node,dim) per thread; unroll-8 with stage prefetch
        int node = t >> 3, d = t & 7;
        int gn = b * NB + node;
        if (gn < N_NODES) {
            float xc = x[(size_t)gn * DIM + d];
            int e = (int)exs[node], eEnd = (int)exs[node + 1];
            float a0 = 0.f, a1 = 0.f, a2 = 0.f, a3 = 0.f;
            for (; e + 8 <= eEnd; e += 8) {
                uint2 q0 = stage[e];
                uint2 q1 = stage[e + 1];
                uint2 q2 = stage[e + 2];
                uint2 q3 = stage[e + 3];
                uint2 q4 = stage[e + 4];
                uint2 q5 = stage[e + 5];
                uint2 q6 = stage[e + 6];
                uint2 q7 = stage[e + 7];
                float s0 = x[(size_t)q0.x * DIM + d];
                float s1 = x[(size_t)q1.x * DIM + d];
                float s2 = x[(size_t)q2.x * DIM + d];
                float s3 = x[(size_t)q3.x * DIM + d];
                float s4 = x[(size_t)q4.x * DIM + d];
                float s5 = x[(size_t)q5.x * DIM + d];
                float s6 = x[(size_t)q6.x * DIM + d];
                float s7 = x[(size_t)q7.x * DIM + d];
                a0 += (s0 - xc) * __uint_as_float(q0.y);
                a1 += (s1 - xc) * __uint_as_float(q1.y);
                a2 += (s2 - xc) * __uint_as_float(q2.y);
                a3 += (s3 - xc) * __uint_as_float(q3.y);
                a0 += (s4 - xc) * __uint_as_float(q4.y);
                a1 += (s5 - xc) * __uint_as_float(q5.y);
                a2 += (s6 - xc) * __uint_as_float(q6.y);
                a3 += (s7 - xc) * __uint_as_float(q7.y);
            }
            for (; e < eEnd; ++e) {
                uint2 p = stage[e];
                a0 += (x[(size_t)p.x * DIM + d] - xc) * __uint_as_float(p.y);
            }
            out[(size_t)gn * DIM + d] = (a0 + a1) + (a2 + a3) - xc;
        }
    } else {
        // overflow guard (statistically impossible): -x init + global atomics
        for (int slot = t; slot < NB * DIM; slot += 1024) {
            int gn = b * NB + (slot >> 3);
            if (gn < N_NODES) {
                size_t gi = (size_t)b * NB * DIM + slot;
                out[gi] = -x[gi];
            }
        }
        __syncthreads();
        int d = t & 7, sub = t >> 3;
        for (int k = sub; k < n; k += 128) {
            uint2 p = payloadA[e0 + k];
            int node = (int)(p.x & (NB - 1));
            int r = (int)(p.x >> BSHIFT);
            int gn = b * NB + node;
            if (gn < N_NODES) {
                float xc = x[(size_t)gn * DIM + d];
                atomicAdd(&out[(size_t)gn * DIM + d],
                          (x[(size_t)r * DIM + d] - xc) * __uint_as_float(p.y));
            }
        }
    }
}

extern "C" void kernel_launch(void* const* d_in, const int* in_sizes, int n_in,
                              void* d_out, int out_size, void* d_ws, size_t ws_size,
                              hipStream_t stream) {
    const float* x   = (const float*)d_in[0];
    const int*   row = (const int*)d_in[1];
    const int*   col = (const int*)d_in[2];
    const float* w   = (const float*)d_in[3];
    float* out = (float*)d_out;
    int nE = in_sizes[1];
    int n4 = out_size / 4;

    int espan = (nE + G1 - 1) / G1;
    espan = (espan + 3) & ~3;            // pad to multiple of 4 (16B-aligned e0)

    auto align256 = [](size_t v) { return (v + 255) & ~(size_t)255; };
    size_t off_payloadA  = 0;
    size_t off_L         = align256(off_payloadA + (size_t)nE * sizeof(uint2));
    size_t off_LT        = align256(off_L  + (size_t)G1 * LSROW * 4);
    size_t off_OT        = align256(off_LT + (size_t)LSROW * G1 * 4);
    size_t off_blockOffs = align256(off_OT + (size_t)NBUCKETS * G1 * 4);
    size_t off_total     = align256(off_blockOffs + (size_t)G1 * NBUCKETS * 4);
    size_t off_start     = align256(off_total + (size_t)NBUCKETS * 4);
    size_t need          = off_start + (size_t)(NBUCKETS + 1) * 4;

    if (ws_size < need || espan > ESPAN_MAX) {
        init_neg_kernel<<<(n4 + 255) / 256, 256, 0, stream>>>(x, out, n4);
        edge_scatter_atomic<<<(nE + 255) / 256, 256, 0, stream>>>(x, row, col, w, out, nE);
        return;
    }

    char* p = (char*)d_ws;
    uint2*    payloadA    = (uint2*)(p + off_payloadA);
    unsigned* L           = (unsigned*)(p + off_L);
    unsigned* LT          = (unsigned*)(p + off_LT);
    unsigned* OT          = (unsigned*)(p + off_OT);
    unsigned* blockOffs   = (unsigned*)(p + off_blockOffs);
    unsigned* bucketTotal = (unsigned*)(p + off_total);
    unsigned* bucketStart = (unsigned*)(p + off_start);

    hist_scan_kernel<<<G1, 256, 0, stream>>>(col, nE, espan, L);
    transpose_kernel<<<dim3((LSROW + 31) / 32, G1 / 32), dim3(32, 8), 0, stream>>>(
        L, LT, G1, LSROW);
    col_scan_kernel<<<NBUCKETS, 1024, 0, stream>>>(LT, OT, bucketTotal);
    bucket_scan_kernel<<<1, 1024, 0, stream>>>(bucketTotal, bucketStart);
    add_transpose_kernel<<<dim3(G1 / 32, (NBUCKETS + 31) / 32), dim3(32, 8), 0, stream>>>(
        OT, bucketStart, blockOffs);
    scatter2_kernel<<<G1, 512, 0, stream>>>(row, col, w, nE, espan, L,
                                            blockOffs, payloadA);
    bucket_sort_gather_kernel<<<NBUCKETS, 1024, 0, stream>>>(x, payloadA,
                                                             bucketStart, out);
}

// Round 17
// 104.127 us; speedup vs baseline: 1.0333x; 1.0333x over previous
//
#include <hip/hip_runtime.h>

#define N_NODES 100000
#define DIM 8
#define NB 128                 // nodes per bucket
#define BSHIFT 7               // log2(NB)
#define NBUCKETS ((N_NODES + NB - 1) / NB)   // 782
#define LSROW (NBUCKETS + 1)   // 783 (local-scan row incl. sentinel)
#define G1 2048                // partition blocks
#define ESPAN_MAX 3328         // LDS stage cap for scatter
#define CAP_H 4800             // max edges per HALF-bucket (mean 4092, ~11 sigma)
#define NPER_H 10              // ceil(CAP_H / 512)

// ---------------- fallback (atomic path) ----------------
__global__ void init_neg_kernel(const float* __restrict__ x,
                                float* __restrict__ out, int n4) {
    int i = blockIdx.x * blockDim.x + threadIdx.x;
    if (i < n4) {
        float4 v = reinterpret_cast<const float4*>(x)[i];
        float4 o; o.x = -v.x; o.y = -v.y; o.z = -v.z; o.w = -v.w;
        reinterpret_cast<float4*>(out)[i] = o;
    }
}

__global__ void edge_scatter_atomic(const float* __restrict__ x,
                                    const int* __restrict__ row,
                                    const int* __restrict__ col,
                                    const float* __restrict__ w,
                                    float* __restrict__ out, int nE) {
    int e = blockIdx.x * blockDim.x + threadIdx.x;
    if (e >= nE) return;
    int r = row[e], c = col[e];
    float we = w[e];
    const float4* xr = reinterpret_cast<const float4*>(x + (size_t)r * DIM);
    const float4* xc = reinterpret_cast<const float4*>(x + (size_t)c * DIM);
    float4 a0 = xr[0], a1 = xr[1], b0 = xc[0], b1 = xc[1];
    float* o = out + (size_t)c * DIM;
    atomicAdd(o + 0, (a0.x - b0.x) * we); atomicAdd(o + 1, (a0.y - b0.y) * we);
    atomicAdd(o + 2, (a0.z - b0.z) * we); atomicAdd(o + 3, (a0.w - b0.w) * we);
    atomicAdd(o + 4, (a1.x - b1.x) * we); atomicAdd(o + 5, (a1.y - b1.y) * we);
    atomicAdd(o + 6, (a1.z - b1.z) * we); atomicAdd(o + 7, (a1.w - b1.w) * we);
}

// ---------------- R17 pipeline ----------------

// K1: per-block histogram (int4 col reads) + LOCAL exclusive scan
__global__ __launch_bounds__(256) void hist_scan_kernel(const int* __restrict__ col,
                                                        int nE, int espan,
                                                        unsigned* __restrict__ L) {
    __shared__ unsigned cnt[NBUCKETS];
    __shared__ unsigned part[256];
    int t = threadIdx.x;
    int p = blockIdx.x;
    int blk = (p & 7) * (G1 / 8) + (p >> 3);   // XCD-chunked swizzle (bijective)
    long e0 = (long)blk * espan;
    long rem = (long)nE - e0;
    int n = (int)(rem > (long)espan ? espan : (rem < 0 ? 0 : rem));

    for (int i = t; i < NBUCKETS; i += 256) cnt[i] = 0;
    __syncthreads();

    const int4* col4 = reinterpret_cast<const int4*>(col + e0);  // e0 16B-aligned
    int nv = n >> 2;
    for (int k = t; k < nv; k += 256) {
        int4 c4 = col4[k];
        atomicAdd(&cnt[((unsigned)c4.x) >> BSHIFT], 1u);
        atomicAdd(&cnt[((unsigned)c4.y) >> BSHIFT], 1u);
        atomicAdd(&cnt[((unsigned)c4.z) >> BSHIFT], 1u);
        atomicAdd(&cnt[((unsigned)c4.w) >> BSHIFT], 1u);
    }
    for (int k = (nv << 2) + t; k < n; k += 256)
        atomicAdd(&cnt[((unsigned)col[e0 + k]) >> BSHIFT], 1u);
    __syncthreads();

    unsigned v[4], s = 0;
    #pragma unroll
    for (int j = 0; j < 4; ++j) {
        int b = 4 * t + j;
        v[j] = (b < NBUCKETS) ? cnt[b] : 0u;
        s += v[j];
    }
    part[t] = s; __syncthreads();
    for (int off = 1; off < 256; off <<= 1) {
        unsigned u = (t >= off) ? part[t - off] : 0u;
        __syncthreads();
        part[t] += u; __syncthreads();
    }
    unsigned base = part[t] - s;
    size_t lrow = (size_t)blk * LSROW;
    #pragma unroll
    for (int j = 0; j < 4; ++j) {
        int b = 4 * t + j;
        if (b < NBUCKETS) { L[lrow + b] = base; base += v[j]; }
    }
    if (t == 255) L[lrow + NBUCKETS] = part[255];   // == n
}

// K2: tile transpose
__global__ void transpose_kernel(const unsigned* __restrict__ in,
                                 unsigned* __restrict__ outp, int R, int C) {
    __shared__ unsigned tile[32][33];
    int tx = threadIdx.x, ty = threadIdx.y;
    int c0 = blockIdx.x * 32, r0 = blockIdx.y * 32;
    #pragma unroll
    for (int j = 0; j < 32; j += 8) {
        int r = r0 + ty + j, c = c0 + tx;
        if (r < R && c < C) tile[ty + j][tx] = in[(size_t)r * C + c];
    }
    __syncthreads();
    #pragma unroll
    for (int j = 0; j < 32; j += 8) {
        int c = c0 + ty + j, r = r0 + tx;
        if (r < R && c < C) outp[(size_t)c * R + r] = tile[tx][ty + j];
    }
}

// K3: per-bucket cross-block scan
__global__ __launch_bounds__(1024) void col_scan_kernel(const unsigned* __restrict__ LT,
                                                        unsigned* __restrict__ OT,
                                                        unsigned* __restrict__ bucketTotal) {
    __shared__ unsigned part[1024];
    int b = blockIdx.x, t = threadIdx.x;
    const unsigned* r0 = LT + (size_t)b * G1;
    const unsigned* r1 = LT + (size_t)(b + 1) * G1;
    unsigned c0 = r1[2 * t] - r0[2 * t];
    unsigned c1 = r1[2 * t + 1] - r0[2 * t + 1];
    part[t] = c0 + c1; __syncthreads();
    for (int off = 1; off < 1024; off <<= 1) {
        unsigned u = (t >= off) ? part[t - off] : 0u;
        __syncthreads();
        part[t] += u; __syncthreads();
    }
    unsigned ex = part[t] - (c0 + c1);
    OT[(size_t)b * G1 + 2 * t]     = ex;
    OT[(size_t)b * G1 + 2 * t + 1] = ex + c0;
    if (t == 1023) bucketTotal[b] = part[1023];
}

// K4: exclusive scan over bucket totals
__global__ __launch_bounds__(1024) void bucket_scan_kernel(const unsigned* __restrict__ bucketTotal,
                                                           unsigned* __restrict__ bucketStart) {
    __shared__ unsigned sc[1024];
    int t = threadIdx.x;
    unsigned v = (t < NBUCKETS) ? bucketTotal[t] : 0u;
    sc[t] = v; __syncthreads();
    for (int off = 1; off < 1024; off <<= 1) {
        unsigned u = (t >= off) ? sc[t - off] : 0u;
        __syncthreads();
        sc[t] += u; __syncthreads();
    }
    if (t < NBUCKETS) bucketStart[t] = sc[t] - v;
    if (t == NBUCKETS - 1) bucketStart[NBUCKETS] = sc[t];
}

// K5: blockOffs[blk][b] = OT[b][blk] + bucketStart[b]
__global__ void add_transpose_kernel(const unsigned* __restrict__ OT,
                                     const unsigned* __restrict__ bucketStart,
                                     unsigned* __restrict__ blockOffs) {
    __shared__ unsigned tile[32][33];
    int tx = threadIdx.x, ty = threadIdx.y;
    int blk0 = blockIdx.x * 32, b0 = blockIdx.y * 32;
    #pragma unroll
    for (int j = 0; j < 32; j += 8) {
        int b = b0 + ty + j, blk = blk0 + tx;
        if (b < NBUCKETS && blk < G1)
            tile[ty + j][tx] = OT[(size_t)b * G1 + blk] + bucketStart[b];
    }
    __syncthreads();
    #pragma unroll
    for (int j = 0; j < 32; j += 8) {
        int blk = blk0 + ty + j, b = b0 + tx;
        if (b < NBUCKETS && blk < G1)
            blockOffs[(size_t)blk * NBUCKETS + b] = tile[tx][ty + j];
    }
}

// K6: single-pass local sort (2-edge vectorized) + coalesced run-flush.
__global__ __launch_bounds__(512) void scatter2_kernel(
        const int* __restrict__ row,
        const int* __restrict__ col,
        const float* __restrict__ w,
        int nE, int espan,
        const unsigned* __restrict__ L,
        const unsigned* __restrict__ blockOffs,
        uint2* __restrict__ payloadA) {
    __shared__ uint2 stage[ESPAN_MAX];           // 26.6 KB
    __shared__ unsigned short sbkt[ESPAN_MAX];   // 6.7 KB
    __shared__ unsigned cur[NBUCKETS];           // 3.1 KB
    __shared__ unsigned diff[NBUCKETS];          // 3.1 KB
    int t = threadIdx.x;
    int p = blockIdx.x;
    int v = (p & 7) * (G1 / 8) + (p >> 3);       // chunked XCD swizzle
    long e0 = (long)v * espan;
    long rem = (long)nE - e0;
    int n = (int)(rem > (long)espan ? espan : (rem < 0 ? 0 : rem));
    size_t lrow = (size_t)v * LSROW;

    for (int i = t; i < NBUCKETS; i += 512) {
        unsigned lv = L[lrow + i];
        cur[i]  = lv;
        diff[i] = blockOffs[(size_t)v * NBUCKETS + i] - lv;
    }
    __syncthreads();

    const int2*   col2 = reinterpret_cast<const int2*>(col + e0);
    const int2*   row2 = reinterpret_cast<const int2*>(row + e0);
    const float2* w2   = reinterpret_cast<const float2*>(w + e0);
    int nv = n >> 1;
    for (int k = t; k < nv; k += 512) {
        int2 c2 = col2[k];
        int2 r2 = row2[k];
        float2 wv = w2[k];
        unsigned b0 = ((unsigned)c2.x) >> BSHIFT;
        unsigned pos0 = atomicAdd(&cur[b0], 1u);
        stage[pos0] = make_uint2(((unsigned)r2.x << BSHIFT) | ((unsigned)c2.x & (NB - 1)),
                                 __float_as_uint(wv.x));
        sbkt[pos0] = (unsigned short)b0;
        unsigned b1 = ((unsigned)c2.y) >> BSHIFT;
        unsigned pos1 = atomicAdd(&cur[b1], 1u);
        stage[pos1] = make_uint2(((unsigned)r2.y << BSHIFT) | ((unsigned)c2.y & (NB - 1)),
                                 __float_as_uint(wv.y));
        sbkt[pos1] = (unsigned short)b1;
    }
    for (int k = (nv << 1) + t; k < n; k += 512) {
        unsigned c = (unsigned)col[e0 + k];
        unsigned b = c >> BSHIFT;
        unsigned pos = atomicAdd(&cur[b], 1u);
        stage[pos] = make_uint2(((unsigned)row[e0 + k] << BSHIFT) | (c & (NB - 1)),
                                __float_as_uint(w[e0 + k]));
        sbkt[pos] = (unsigned short)b;
    }
    __syncthreads();

    for (int k = t; k < n; k += 512) {
        unsigned b = sbkt[k];
        payloadA[diff[b] + (unsigned)k] = stage[k];
    }
}

// K7 (NEW): half-bucket sort+gather. Block i = (bucket b = i/2, half h = i%2).
// 512 threads, ~39.9 KB LDS -> 4 blocks/CU = 32 waves. Rank-from-count trick:
// the count atomicAdd's return value IS the within-node rank (no 2nd atomic).
// Writes 1024 partial sums coalesced; reduce kernel combines halves + (-x).
__global__ __launch_bounds__(512, 8) void bucket_half_kernel(
        const float* __restrict__ x,
        const uint2* __restrict__ payloadA,
        const unsigned* __restrict__ bucketStart,
        float* __restrict__ partials) {
    __shared__ uint2 stage[CAP_H];        // 38.4 KB
    __shared__ unsigned cnt[NB];
    __shared__ unsigned scanb[NB];
    __shared__ unsigned exs[NB + 1];
    int i = blockIdx.x;
    int b = i >> 1, h = i & 1;
    int t = threadIdx.x;
    int e0b = (int)bucketStart[b], e1b = (int)bucketStart[b + 1];
    int n = e1b - e0b;
    int n2 = n >> 1;
    int hs = h ? n2 : 0;
    int he = h ? n : n2;
    int nh = he - hs;
    int e0 = e0b + hs;
    float* myp = partials + (size_t)i * (NB * DIM);

    if (t < NB) cnt[t] = 0;
    __syncthreads();

    if (nh <= CAP_H) {
        // pass 1: coalesced load into regs + count (rank = atomic return)
        uint2 regs[NPER_H];
        unsigned short rk[NPER_H];
        #pragma unroll
        for (int j = 0; j < NPER_H; ++j) {
            int k = (j << 9) + t;
            if (k < nh) {
                uint2 p = payloadA[e0 + k];
                regs[j] = p;
                rk[j] = (unsigned short)atomicAdd(&cnt[p.x & (NB - 1)], 1u);
            }
        }
        __syncthreads();
        if (t < NB) scanb[t] = cnt[t];
        __syncthreads();
        for (int off = 1; off < NB; off <<= 1) {
            unsigned v = 0;
            if (t < NB && t >= off) v = scanb[t - off];
            __syncthreads();
            if (t < NB) scanb[t] += v;
            __syncthreads();
        }
        if (t < NB) exs[t] = scanb[t] - cnt[t];
        if (t == 0) exs[NB] = (unsigned)nh;
        __syncthreads();

        // pass 2: place from regs at exs[node]+rank (no atomics)
        #pragma unroll
        for (int j = 0; j < NPER_H; ++j) {
            int k = (j << 9) + t;
            if (k < nh) {
                uint2 p = regs[j];
                stage[exs[p.x & (NB - 1)] + (unsigned)rk[j]] =
                    make_uint2(p.x >> BSHIFT, p.y);
            }
        }
        __syncthreads();

        // gather: 2 slots per thread, unroll-4
        #pragma unroll
        for (int s = 0; s < 2; ++s) {
            int slot = t + (s << 9);
            int node = slot >> 3, d = slot & 7;
            int gn = b * NB + node;
            if (gn < N_NODES) {
                float xc = x[(size_t)gn * DIM + d];
                int e = (int)exs[node], eEnd = (int)exs[node + 1];
                float a0 = 0.f, a1 = 0.f;
                for (; e + 4 <= eEnd; e += 4) {
                    uint2 p0 = stage[e];
                    uint2 p1 = stage[e + 1];
                    uint2 p2 = stage[e + 2];
                    uint2 p3 = stage[e + 3];
                    float s0 = x[(size_t)p0.x * DIM + d];
                    float s1 = x[(size_t)p1.x * DIM + d];
                    float s2 = x[(size_t)p2.x * DIM + d];
                    float s3 = x[(size_t)p3.x * DIM + d];
                    a0 += (s0 - xc) * __uint_as_float(p0.y);
                    a1 += (s1 - xc) * __uint_as_float(p1.y);
                    a0 += (s2 - xc) * __uint_as_float(p2.y);
                    a1 += (s3 - xc) * __uint_as_float(p3.y);
                }
                for (; e < eEnd; ++e) {
                    uint2 p = stage[e];
                    a0 += (x[(size_t)p.x * DIM + d] - xc) * __uint_as_float(p.y);
                }
                myp[slot] = a0 + a1;
            } else {
                myp[slot] = 0.f;   // fully overwrite poisoned partials
            }
        }
    } else {
        // overflow guard (statistically impossible): zero + global atomics
        for (int s = t; s < NB * DIM; s += 512) myp[s] = 0.f;
        __syncthreads();
        int d = t & 7, sub = t >> 3;
        for (int k = sub; k < nh; k += 64) {
            uint2 p = payloadA[e0 + k];
            int node = (int)(p.x & (NB - 1));
            int gn = b * NB + node;
            if (gn < N_NODES) {
                float xc = x[(size_t)gn * DIM + d];
                atomicAdd(&myp[node * DIM + d],
                          (x[(size_t)(p.x >> BSHIFT) * DIM + d] - xc) * __uint_as_float(p.y));
            }
        }
    }
}

// K8: out = partials[2b] + partials[2b+1] - x   (coalesced)
__global__ __launch_bounds__(1024) void reduce_out_kernel(
        const float* __restrict__ x,
        const float* __restrict__ partials,
        float* __restrict__ out) {
    int b = blockIdx.x, t = threadIdx.x;
    int gn = b * NB + (t >> 3);
    if (gn >= N_NODES) return;
    size_t gi = (size_t)b * (NB * DIM) + t;   // == gn*DIM + d
    out[gi] = partials[(size_t)(2 * b) * (NB * DIM) + t]
            + partials[(size_t)(2 * b + 1) * (NB * DIM) + t]
            - x[gi];
}

extern "C" void kernel_launch(void* const* d_in, const int* in_sizes, int n_in,
                              void* d_out, int out_size, void* d_ws, size_t ws_size,
                              hipStream_t stream) {
    const float* x   = (const float*)d_in[0];
    const int*   row = (const int*)d_in[1];
    const int*   col = (const int*)d_in[2];
    const float* w   = (const float*)d_in[3];
    float* out = (float*)d_out;
    int nE = in_sizes[1];
    int n4 = out_size / 4;

    int espan = (nE + G1 - 1) / G1;
    espan = (espan + 3) & ~3;            // pad to multiple of 4 (16B-aligned e0)

    auto align256 = [](size_t v) { return (v + 255) & ~(size_t)255; };
    size_t off_payloadA  = 0;
    size_t off_L         = align256(off_payloadA + (size_t)nE * sizeof(uint2));
    size_t off_LT        = align256(off_L  + (size_t)G1 * LSROW * 4);
    size_t off_OT        = align256(off_LT + (size_t)LSROW * G1 * 4);
    size_t off_blockOffs = align256(off_OT + (size_t)NBUCKETS * G1 * 4);
    size_t off_total     = align256(off_blockOffs + (size_t)G1 * NBUCKETS * 4);
    size_t off_start     = align256(off_total + (size_t)NBUCKETS * 4);
    size_t off_partials  = align256(off_start + (size_t)(NBUCKETS + 1) * 4);
    size_t need          = off_partials + (size_t)2 * NBUCKETS * NB * DIM * 4;

    if (ws_size < need || espan > ESPAN_MAX) {
        init_neg_kernel<<<(n4 + 255) / 256, 256, 0, stream>>>(x, out, n4);
        edge_scatter_atomic<<<(nE + 255) / 256, 256, 0, stream>>>(x, row, col, w, out, nE);
        return;
    }

    char* p = (char*)d_ws;
    uint2*    payloadA    = (uint2*)(p + off_payloadA);
    unsigned* L           = (unsigned*)(p + off_L);
    unsigned* LT          = (unsigned*)(p + off_LT);
    unsigned* OT          = (unsigned*)(p + off_OT);
    unsigned* blockOffs   = (unsigned*)(p + off_blockOffs);
    unsigned* bucketTotal = (unsigned*)(p + off_total);
    unsigned* bucketStart = (unsigned*)(p + off_start);
    float*    partials    = (float*)(p + off_partials);

    hist_scan_kernel<<<G1, 256, 0, stream>>>(col, nE, espan, L);
    transpose_kernel<<<dim3((LSROW + 31) / 32, G1 / 32), dim3(32, 8), 0, stream>>>(
        L, LT, G1, LSROW);
    col_scan_kernel<<<NBUCKETS, 1024, 0, stream>>>(LT, OT, bucketTotal);
    bucket_scan_kernel<<<1, 1024, 0, stream>>>(bucketTotal, bucketStart);
    add_transpose_kernel<<<dim3(G1 / 32, (NBUCKETS + 31) / 32), dim3(32, 8), 0, stream>>>(
        OT, bucketStart, blockOffs);
    scatter2_kernel<<<G1, 512, 0, stream>>>(row, col, w, nE, espan, L,
                                            blockOffs, payloadA);
    bucket_half_kernel<<<2 * NBUCKETS, 512, 0, stream>>>(x, payloadA,
                                                         bucketStart, partials);
    reduce_out_kernel<<<NBUCKETS, 1024, 0, stream>>>(x, partials, out);
}